// Round 5
// baseline (3040.315 us; speedup 1.0000x reference)
//
#include <hip/hip_runtime.h>
#include <math.h>

#define Bb 64
#define Pp 196
#define ENCd 2048
#define Lc 20
#define Tt 19
#define Vv 10000
#define Ee 512
#define Dd 512
#define Aa 512
#define K2 2560     // E + ENC   (x3 = [emb | gate*awe])
#define KG 3072     // E + ENC + D
#define G4 2048

#define OUT_PRED 0ll
#define OUT_CAPS 12160000ll   // B*T*V
#define OUT_ALPH 12161280ll   // + B*L
#define OUT_SIND 12399616ll   // + B*T*P

typedef unsigned short ushort_t;
typedef __attribute__((ext_vector_type(8))) short short8;
typedef __attribute__((ext_vector_type(4))) float f32x4;

#define MFMA16 __builtin_amdgcn_mfma_f32_16x16x32_bf16

__device__ __forceinline__ float b2f(ushort_t u) {
    union { unsigned int i; float f; } x; x.i = ((unsigned int)u) << 16; return x.f;
}
__device__ __forceinline__ ushort_t f2b(float f) {
    union { float f; unsigned int i; } x; x.f = f;
    unsigned int r = x.i + 0x7fffu + ((x.i >> 16) & 1u);
    return (ushort_t)(r >> 16);
}
__device__ __forceinline__ float fsig(float x) { return 1.0f / (1.0f + __expf(-x)); }
__device__ __forceinline__ float ftanh(float x) {
    x = fminf(fmaxf(x, -15.0f), 15.0f);
    float e = __expf(2.0f * x);
    return (e - 1.0f) / (e + 1.0f);
}

// ---------------- sort ------------------------------------------------------
__global__ void k_sort(const int* __restrict__ cap_len, const int* __restrict__ caps_in,
                       float* __restrict__ out, int* __restrict__ sind,
                       int* __restrict__ dlen, int* __restrict__ caps_s) {
    __shared__ int cls[Bb];
    int i = threadIdx.x;
    int cl = cap_len[i];
    cls[i] = cl;
    __syncthreads();
    int rank = 0;
    for (int j = 0; j < Bb; ++j) {
        int cj = cls[j];
        rank += (cj > cl) || (cj == cl && j < i);
    }
    sind[rank] = i;
    dlen[rank] = cl - 1;
    out[OUT_SIND + rank] = (float)i;
    for (int l = 0; l < Lc; ++l) {
        int v = caps_in[i * Lc + l];
        caps_s[rank * Lc + l] = v;
        out[OUT_CAPS + rank * Lc + l] = (float)v;
    }
}

// ---------------- merged weight conversions (with gate-interleave remap) -----
__device__ __forceinline__ void cvtseg(const float* __restrict__ src, ushort_t* __restrict__ dst,
                                       int cols, int stride, int off, int bid0,
                                       long long quads, int remap) {
    long long qid = (long long)bid0 * 256 + threadIdx.x;
    if (qid >= quads) return;
    int c4pr = cols >> 2;
    int r = (int)(qid / c4pr), c4 = (int)(qid % c4pr) << 2;
    float4 v = *(const float4*)&src[(size_t)r * cols + c4];
    ushort4 o; o.x = f2b(v.x); o.y = f2b(v.y); o.z = f2b(v.z); o.w = f2b(v.w);
    int dr = remap ? (((r & 511) << 2) | (r >> 9)) : r;
    *(ushort4*)&dst[(size_t)dr * stride + off + c4] = o;
}

__global__ void k_cvtall(const float* Wdec, const float* Wfb, const float* Wih,
                         const float* Whh, const float* Wfc, const float* Wenc_f,
                         const float* Wih0, const float* Wic0,
                         ushort_t* W_ag, ushort_t* W_cat2, ushort_t* W_fcb,
                         ushort_t* W_enc, ushort_t* W_hcb) {
    int b = blockIdx.x;
    if      (b < 256)   cvtseg(Wdec,  W_ag,               512,  512,  0,    b,         65536,   0);
    else if (b < 1280)  cvtseg(Wfb,   W_ag + 512 * 512,   512,  512,  0,    b - 256,   262144,  0);
    else if (b < 6400)  cvtseg(Wih,   W_cat2,             2560, 3072, 0,    b - 1280,  1310720, 1);
    else if (b < 7424)  cvtseg(Whh,   W_cat2,             512,  3072, 2560, b - 6400,  262144,  1);
    else if (b < 12424) cvtseg(Wfc,   W_fcb,              512,  512,  0,    b - 7424,  1280000, 0);
    else if (b < 13448) cvtseg(Wenc_f,W_enc,              2048, 2048, 0,    b - 12424, 262144,  0);
    else if (b < 14472) cvtseg(Wih0,  W_hcb,              2048, 2048, 0,    b - 13448, 262144,  0);
    else                cvtseg(Wic0,  W_hcb + 512 * 2048, 2048, 2048, 0,    b - 14472, 262144,  0);
}

// ---------------- bias prep --------------------------------------------------
__global__ void k_bias(const float* b_dec, const float* b_fb, const float* b_ihp,
                       const float* b_hhp, const float* b_h, const float* b_c,
                       float* b_ag, float* bsum, float* b_hc) {
    int id = blockIdx.x * 256 + threadIdx.x;
    if (id < 512) b_ag[id] = b_dec[id];
    else if (id < 2560) b_ag[id] = b_fb[id - 512];
    if (id < 2048) bsum[id] = b_ihp[id] + b_hhp[id];
    if (id < 512) b_hc[id] = b_h[id];
    else if (id < 1024) b_hc[id] = b_c[id - 512];
}

// ---------------- gather+convert encoder_out (sorted) -> bf16 ----------------
__global__ void __launch_bounds__(256) k_enccvt(const float* __restrict__ enc,
                                                const int* __restrict__ sind,
                                                ushort_t* __restrict__ enc_bf) {
    int r = blockIdx.x;                 // 12544 rows
    int b = r / Pp;
    size_t srow = (size_t)sind[b] * Pp + (r - b * Pp);
    int e8 = threadIdx.x * 8;
    const float* s = enc + srow * ENCd + e8;
    float4 v0 = *(const float4*)s;
    float4 v1 = *(const float4*)(s + 4);
    short8 o;
    o[0] = (short)f2b(v0.x); o[1] = (short)f2b(v0.y); o[2] = (short)f2b(v0.z); o[3] = (short)f2b(v0.w);
    o[4] = (short)f2b(v1.x); o[5] = (short)f2b(v1.y); o[6] = (short)f2b(v1.z); o[7] = (short)f2b(v1.w);
    *(short8*)&enc_bf[(size_t)r * ENCd + e8] = o;
}

// ---------------- mean over pixels -------------------------------------------
__global__ void __launch_bounds__(1024) k_meanenc(const ushort_t* __restrict__ enc_bf,
                                                  ushort_t* __restrict__ mean_bf) {
    int b = blockIdx.x;
    int lane = threadIdx.x & 63, w = threadIdx.x >> 6;
    int cg = w & 3, pg = w >> 2;
    int lc = cg * 512 + lane * 8;
    __shared__ float red[4][2048];
    float acc[8] = {};
    for (int p = pg; p < Pp; p += 4) {
        short8 v = *(const short8*)&enc_bf[((size_t)b * Pp + p) * ENCd + lc];
        #pragma unroll
        for (int j = 0; j < 8; ++j) acc[j] += b2f((ushort_t)v[j]);
    }
    #pragma unroll
    for (int j = 0; j < 8; ++j) red[pg][lc + j] = acc[j];
    __syncthreads();
    int tid = threadIdx.x;
    float2 s = {0.f, 0.f};
    #pragma unroll
    for (int g = 0; g < 4; ++g) {
        float2 v = *(const float2*)&red[g][tid * 2];
        s.x += v.x; s.y += v.y;
    }
    ushort2 o; o.x = f2b(s.x * (1.0f / Pp)); o.y = f2b(s.y * (1.0f / Pp));
    *(ushort2*)&mean_bf[(size_t)b * ENCd + tid * 2] = o;
}

// ---------------- persistent megakernel --------------------------------------
struct MegaArgs {
    const ushort_t* enc_bf;
    const ushort_t* mean_bf;
    const ushort_t* W_enc;
    const ushort_t* W_hcb;
    const ushort_t* W_ag;
    const ushort_t* W_cat2;
    const ushort_t* W_fcb;
    const float* b_enc; const float* b_hc; const float* b_ag;
    const float* bsum;  const float* b_fc;
    const float* wfull; const float* bfull;
    const float* emb;   const int* caps_s; const int* dlen;
    ushort_t* att1;     // [12544*512]
    ushort_t* hball;    // [20*64*512]
    float* c_st; float* ag; float* alphaBuf; ushort_t* x3;
    float* out;
    unsigned* bar;
};

__device__ __forceinline__ void gridbar(unsigned* bar) {
    __syncthreads();
    if (threadIdx.x == 0) {
        __threadfence();
        unsigned old = __hip_atomic_fetch_add(bar, 1u, __ATOMIC_RELAXED, __HIP_MEMORY_SCOPE_AGENT);
        unsigned target = (old / 256u + 1u) * 256u;
        while (__hip_atomic_load(bar, __ATOMIC_RELAXED, __HIP_MEMORY_SCOPE_AGENT) < target)
            __builtin_amdgcn_s_sleep(2);
        __threadfence();
    }
    __syncthreads();
}

__device__ __forceinline__ void reduce16(f32x4* acc, f32x4 (*red)[4][64], int w, int lane) {
    for (int s = 8; s; s >>= 1) {
        if (w >= s && w < 2 * s) {
            #pragma unroll
            for (int mt = 0; mt < 4; ++mt) red[w - s][mt][lane] = acc[mt];
        }
        __syncthreads();
        if (w < s) {
            #pragma unroll
            for (int mt = 0; mt < 4; ++mt) acc[mt] += red[w][mt][lane];
        }
        __syncthreads();
    }
}

__global__ void __launch_bounds__(1024, 4) k_mega(MegaArgs A) {
    const int blk = blockIdx.x;
    const int tid = threadIdx.x;
    const int lane = tid & 63, w = tid >> 6;
    const int r16 = lane & 15, kq = (lane >> 4) << 3;
    const int rj0 = (lane >> 4) << 2;

    __shared__ f32x4 red4[8][4][64];     // 32 KB (split-K reduce / awe reduce)
    __shared__ float gbuf[64][17];       // LSTM gate staging
    __shared__ float smA[256];
    __shared__ float smB[256];

    // ================= P0: att1 (units 0..783) + h0/c0 (784..847) ===========
    for (int u = blk; u < 848; u += 256) {
        if (u < 784) {
            int m0 = u * 16;
            const ushort_t* ap = A.enc_bf + (size_t)(m0 + r16) * ENCd + kq;
            int nb = w * 32;
            const ushort_t* wp0 = A.W_enc + (size_t)(nb + r16) * ENCd + kq;
            const ushort_t* wp1 = wp0 + (size_t)16 * ENCd;
            f32x4 acc0 = (f32x4){0,0,0,0}, acc1 = (f32x4){0,0,0,0};
            for (int k0 = 0; k0 < ENCd; k0 += 32) {
                short8 a  = *(const short8*)(ap + k0);
                short8 b0 = *(const short8*)(wp0 + k0);
                short8 b1 = *(const short8*)(wp1 + k0);
                acc0 = MFMA16(a, b0, acc0, 0, 0, 0);
                acc1 = MFMA16(a, b1, acc1, 0, 0, 0);
            }
            #pragma unroll
            for (int j = 0; j < 4; ++j) {
                int row = m0 + rj0 + j;
                int c0 = nb + r16, c1 = nb + 16 + r16;
                A.att1[(size_t)row * Aa + c0] = f2b(acc0[j] + A.b_enc[c0]);
                A.att1[(size_t)row * Aa + c1] = f2b(acc1[j] + A.b_enc[c1]);
            }
        } else {
            int ct = u - 784;
            int n0 = ct * 16;
            f32x4 acc[4];
            #pragma unroll
            for (int mt = 0; mt < 4; ++mt) acc[mt] = (f32x4){0,0,0,0};
            const ushort_t* wp = A.W_hcb + (size_t)(n0 + r16) * ENCd + kq;
            for (int k0 = w * 128; k0 < w * 128 + 128; k0 += 32) {
                short8 b8 = *(const short8*)(wp + k0);
                #pragma unroll
                for (int mt = 0; mt < 4; ++mt) {
                    short8 a = *(const short8*)(A.mean_bf + (size_t)(mt * 16 + r16) * ENCd + k0 + kq);
                    acc[mt] = MFMA16(a, b8, acc[mt], 0, 0, 0);
                }
            }
            reduce16(acc, red4, w, lane);
            if (w == 0) {
                int col = n0 + r16;
                #pragma unroll
                for (int mt = 0; mt < 4; ++mt)
                    #pragma unroll
                    for (int j = 0; j < 4; ++j) {
                        int row = mt * 16 + rj0 + j;
                        float v = acc[mt][j] + A.b_hc[col];
                        if (col < 512) A.hball[(size_t)row * Dd + col] = f2b(v);
                        else           A.c_st[row * Dd + (col - 512)] = v;
                    }
            }
        }
    }
    gridbar(A.bar);

    // ================= time loop ============================================
    for (int t = 0; t < Tt; ++t) {
        const ushort_t* hcur = A.hball + (size_t)t * Bb * Dd;
        // ---- Phase A: ag GEMM (blk<160) + emb gather (blk>=160) ----
        if (blk < 160) {
            int n0 = blk * 16;
            f32x4 acc[4];
            #pragma unroll
            for (int mt = 0; mt < 4; ++mt) acc[mt] = (f32x4){0,0,0,0};
            {
                int k0 = w * 32;
                short8 b8 = *(const short8*)(A.W_ag + (size_t)(n0 + r16) * Dd + k0 + kq);
                #pragma unroll
                for (int mt = 0; mt < 4; ++mt) {
                    short8 a = *(const short8*)(hcur + (size_t)(mt * 16 + r16) * Dd + k0 + kq);
                    acc[mt] = MFMA16(a, b8, acc[mt], 0, 0, 0);
                }
            }
            reduce16(acc, red4, w, lane);
            if (w == 0) {
                int col = n0 + r16;
                float bv = A.b_ag[col];
                #pragma unroll
                for (int mt = 0; mt < 4; ++mt)
                    #pragma unroll
                    for (int j = 0; j < 4; ++j) {
                        int row = mt * 16 + rj0 + j;
                        float v = acc[mt][j] + bv;
                        A.ag[(size_t)row * K2 + col] = (col >= 512) ? fsig(v) : v;
                    }
            }
        } else {
            int gid = (blk - 160) * 1024 + tid;
            if (gid < 16384) {
                int b = gid >> 8, k2 = (gid & 255) * 2;
                float2 e = *(const float2*)&A.emb[(size_t)A.caps_s[b * Lc + t] * Ee + k2];
                ushort2 o; o.x = f2b(e.x); o.y = f2b(e.y);
                *(ushort2*)&A.x3[(size_t)b * K2 + k2] = o;
            }
        }
        gridbar(A.bar);

        // ---- Phase B: e-score + softmax (blocks 160..223) ----
        if (blk >= 160 && blk < 224) {
            int b = blk - 160;
            float a2[8], wf[8];
            {
                const float* a2p = A.ag + (size_t)b * K2 + lane * 8;
                float4 x0 = *(const float4*)a2p, x1 = *(const float4*)(a2p + 4);
                a2[0]=x0.x; a2[1]=x0.y; a2[2]=x0.z; a2[3]=x0.w;
                a2[4]=x1.x; a2[5]=x1.y; a2[6]=x1.z; a2[7]=x1.w;
                const float* wp = A.wfull + lane * 8;
                float4 y0 = *(const float4*)wp, y1 = *(const float4*)(wp + 4);
                wf[0]=y0.x; wf[1]=y0.y; wf[2]=y0.z; wf[3]=y0.w;
                wf[4]=y1.x; wf[5]=y1.y; wf[6]=y1.z; wf[7]=y1.w;
            }
            for (int p = w; p < Pp; p += 16) {
                short8 a1 = *(const short8*)&A.att1[((size_t)b * Pp + p) * Aa + lane * 8];
                float s = 0.f;
                #pragma unroll
                for (int j = 0; j < 8; ++j)
                    s += ftanh(b2f((ushort_t)a1[j]) + a2[j]) * wf[j];
                #pragma unroll
                for (int o = 32; o; o >>= 1) s += __shfl_xor(s, o);
                if (lane == 0) smB[p] = s + A.bfull[0];
            }
            __syncthreads();
            float v = (tid < Pp) ? smB[tid] : -1e30f;
            if (tid < 256) smA[tid] = v;
            __syncthreads();
            for (int o = 128; o; o >>= 1) {
                if (tid < o) smA[tid] = fmaxf(smA[tid], smA[tid + o]);
                __syncthreads();
            }
            float mx = smA[0];
            __syncthreads();
            float ex = (tid < Pp) ? __expf(v - mx) : 0.0f;
            if (tid < 256) smA[tid] = ex;
            __syncthreads();
            for (int o = 128; o; o >>= 1) {
                if (tid < o) smA[tid] += smA[tid + o];
                __syncthreads();
            }
            float denom = smA[0];
            if (tid < Pp) {
                float al = ex / denom;
                A.alphaBuf[b * Pp + tid] = al;
                A.out[OUT_ALPH + ((long long)b * Tt + t) * Pp + tid] = (t < A.dlen[b]) ? al : 0.0f;
            }
        }
        gridbar(A.bar);

        // ---- Phase C: awe = alpha . enc ; x3[:,512:] = bf16(gate*awe) ----
        {
            int b = blk >> 2, ch = blk & 3;
            if (tid < Pp) smA[tid] = A.alphaBuf[b * Pp + tid];
            __syncthreads();
            f32x4 acA = (f32x4){0,0,0,0}, acB = (f32x4){0,0,0,0};
            const ushort_t* ep = A.enc_bf + ((size_t)b * Pp) * ENCd + ch * 512 + lane * 8;
            for (int p = w; p < Pp; p += 16) {
                float a = smA[p];
                short8 v = *(const short8*)(ep + (size_t)p * ENCd);
                acA[0] += a * b2f((ushort_t)v[0]); acA[1] += a * b2f((ushort_t)v[1]);
                acA[2] += a * b2f((ushort_t)v[2]); acA[3] += a * b2f((ushort_t)v[3]);
                acB[0] += a * b2f((ushort_t)v[4]); acB[1] += a * b2f((ushort_t)v[5]);
                acB[2] += a * b2f((ushort_t)v[6]); acB[3] += a * b2f((ushort_t)v[7]);
            }
            float* redf = (float*)red4;     // 16 waves x 512 floats
            *(f32x4*)&redf[w * 512 + lane * 8]     = acA;
            *(f32x4*)&redf[w * 512 + lane * 8 + 4] = acB;
            __syncthreads();
            if (tid < 512) {
                float s = 0.f;
                #pragma unroll
                for (int g = 0; g < 16; ++g) s += redf[g * 512 + tid];
                int col = ch * 512 + tid;
                float gte = A.ag[(size_t)b * K2 + 512 + col];
                A.x3[(size_t)b * K2 + Ee + col] = f2b(gte * s);
            }
        }
        gridbar(A.bar);

        // ---- Phase D: gates GEMM + LSTM (blocks 0..127) ----
        if (blk < 128) {
            f32x4 acc[4];
            #pragma unroll
            for (int mt = 0; mt < 4; ++mt) acc[mt] = (f32x4){0,0,0,0};
            const ushort_t* wp = A.W_cat2 + (size_t)(blk * 16 + r16) * KG + kq;
            for (int k0 = w * 192; k0 < w * 192 + 192; k0 += 32) {
                short8 b8 = *(const short8*)(wp + k0);
                const ushort_t* abase = (k0 < K2) ? (A.x3 + k0) : (hcur + (k0 - K2));
                int stride = (k0 < K2) ? K2 : Dd;
                #pragma unroll
                for (int mt = 0; mt < 4; ++mt) {
                    short8 a = *(const short8*)(abase + (size_t)(mt * 16 + r16) * stride + kq);
                    acc[mt] = MFMA16(a, b8, acc[mt], 0, 0, 0);
                }
            }
            reduce16(acc, red4, w, lane);
            if (w == 0) {
                #pragma unroll
                for (int mt = 0; mt < 4; ++mt)
                    #pragma unroll
                    for (int j = 0; j < 4; ++j)
                        gbuf[mt * 16 + rj0 + j][r16] = acc[mt][j];
            }
            __syncthreads();
            if (tid < 256) {
                int row = tid >> 2, q = tid & 3;
                int d = blk * 4 + q;
                ushort_t* hnew = A.hball + (size_t)(t + 1) * Bb * Dd;
                if (t < A.dlen[row]) {
                    float gi = gbuf[row][q * 4 + 0] + A.bsum[d];
                    float gf = gbuf[row][q * 4 + 1] + A.bsum[512 + d];
                    float gg = gbuf[row][q * 4 + 2] + A.bsum[1024 + d];
                    float go = gbuf[row][q * 4 + 3] + A.bsum[1536 + d];
                    float cv = A.c_st[row * Dd + d];
                    float cn = fsig(gf) * cv + fsig(gi) * ftanh(gg);
                    A.c_st[row * Dd + d] = cn;
                    hnew[row * Dd + d] = f2b(fsig(go) * ftanh(cn));
                } else {
                    hnew[row * Dd + d] = hcur[row * Dd + d];
                }
            }
        }
        gridbar(A.bar);
    }

    // ================= batched preds: [19*64] x 10000 x 512 ==================
    for (int u = blk; u < 625; u += 256) {
        int n0 = u * 16;
        const ushort_t* wp = A.W_fcb + (size_t)(n0 + r16) * Dd + kq;
        for (int f = w; f < 76; f += 16) {
            f32x4 acc = (f32x4){0,0,0,0};
            const ushort_t* ap = A.hball + (size_t)(64 + f * 16 + r16) * Dd + kq;
            #pragma unroll 4
            for (int k0 = 0; k0 < Dd; k0 += 32)
                acc = MFMA16(*(const short8*)(ap + k0), *(const short8*)(wp + k0), acc, 0, 0, 0);
            int col = n0 + r16;
            float bv = A.b_fc[col];
            #pragma unroll
            for (int j = 0; j < 4; ++j) {
                int row = f * 16 + rj0 + j;
                int ts = row >> 6, b = row & 63;
                A.out[OUT_PRED + ((long long)b * Tt + ts) * Vv + col] =
                    (ts < A.dlen[b]) ? acc[j] + bv : 0.0f;
            }
        }
    }
}

extern "C" void kernel_launch(void* const* d_in, const int* in_sizes, int n_in,
                              void* d_out, int out_size, void* d_ws, size_t ws_size,
                              hipStream_t stream) {
    const float* encoder_out      = (const float*)d_in[0];
    const int*   encoded_captions = (const int*)d_in[1];
    const int*   caption_lengths  = (const int*)d_in[2];
    const float* emb       = (const float*)d_in[3];
    const float* W_ih      = (const float*)d_in[4];
    const float* b_ih      = (const float*)d_in[5];
    const float* W_hh      = (const float*)d_in[6];
    const float* b_hh      = (const float*)d_in[7];
    const float* W_init_h  = (const float*)d_in[8];
    const float* b_init_h  = (const float*)d_in[9];
    const float* W_init_c  = (const float*)d_in[10];
    const float* b_init_c  = (const float*)d_in[11];
    const float* W_fbeta   = (const float*)d_in[12];
    const float* b_fbeta   = (const float*)d_in[13];
    const float* W_fc      = (const float*)d_in[14];
    const float* b_fc      = (const float*)d_in[15];
    const float* W_enc_att = (const float*)d_in[16];
    const float* b_enc_att = (const float*)d_in[17];
    const float* W_dec_att = (const float*)d_in[18];
    const float* b_dec_att = (const float*)d_in[19];
    const float* W_full_att = (const float*)d_in[20];
    const float* b_full_att = (const float*)d_in[21];
    float* out = (float*)d_out;

    char* p = (char*)d_ws;
    auto alloc = [&](size_t bytes) { char* r = p; p += (bytes + 255) & ~255ull; return r; };
    unsigned* bar = (unsigned*)alloc(256);
    int* sind   = (int*)alloc(64 * 4);
    int* dlen   = (int*)alloc(64 * 4);
    int* caps_s = (int*)alloc(Bb * Lc * 4);
    float* c_st     = (float*)alloc(Bb * Dd * 4);
    float* ag       = (float*)alloc((size_t)Bb * K2 * 4);
    float* alphaBuf = (float*)alloc(Bb * Pp * 4);
    float* b_ag  = (float*)alloc(K2 * 4);
    float* bsum  = (float*)alloc(G4 * 4);
    float* b_hc  = (float*)alloc(1024 * 4);
    ushort_t* mean_bf = (ushort_t*)alloc((size_t)Bb * ENCd * 2);
    ushort_t* hball   = (ushort_t*)alloc((size_t)(Tt + 1) * Bb * Dd * 2);  // 1.31 MB
    ushort_t* x3      = (ushort_t*)alloc((size_t)Bb * K2 * 2);
    ushort_t* att1    = (ushort_t*)alloc((size_t)Bb * Pp * Aa * 2);        // 12.85 MB
    ushort_t* W_enc   = (ushort_t*)alloc((size_t)Aa * ENCd * 2);
    ushort_t* W_ag    = (ushort_t*)alloc((size_t)K2 * Dd * 2);
    ushort_t* W_cat2  = (ushort_t*)alloc((size_t)G4 * KG * 2);
    ushort_t* W_fcb   = (ushort_t*)alloc((size_t)Vv * Dd * 2);
    ushort_t* W_hcb   = (ushort_t*)alloc((size_t)1024 * ENCd * 2);
    ushort_t* enc_bf  = (ushort_t*)alloc((size_t)Bb * Pp * ENCd * 2);      // 51.4 MB

    (void)hipMemsetAsync(bar, 0, 4, stream);
    k_sort<<<1, 64, 0, stream>>>(caption_lengths, encoded_captions, out, sind, dlen, caps_s);
    k_cvtall<<<15496, 256, 0, stream>>>(W_dec_att, W_fbeta, W_ih, W_hh, W_fc, W_enc_att,
                                        W_init_h, W_init_c, W_ag, W_cat2, W_fcb, W_enc, W_hcb);
    k_bias<<<10, 256, 0, stream>>>(b_dec_att, b_fbeta, b_ih, b_hh, b_init_h, b_init_c,
                                   b_ag, bsum, b_hc);
    k_enccvt<<<12544, 256, 0, stream>>>(encoder_out, sind, enc_bf);
    k_meanenc<<<64, 1024, 0, stream>>>(enc_bf, mean_bf);

    MegaArgs ma;
    ma.enc_bf = enc_bf; ma.mean_bf = mean_bf;
    ma.W_enc = W_enc; ma.W_hcb = W_hcb; ma.W_ag = W_ag; ma.W_cat2 = W_cat2; ma.W_fcb = W_fcb;
    ma.b_enc = b_enc_att; ma.b_hc = b_hc; ma.b_ag = b_ag; ma.bsum = bsum; ma.b_fc = b_fc;
    ma.wfull = W_full_att; ma.bfull = b_full_att;
    ma.emb = emb; ma.caps_s = caps_s; ma.dlen = dlen;
    ma.att1 = att1; ma.hball = hball; ma.c_st = c_st; ma.ag = ag;
    ma.alphaBuf = alphaBuf; ma.x3 = x3; ma.out = out; ma.bar = bar;
    k_mega<<<256, 1024, 0, stream>>>(ma);
}

// Round 6
// 1937.130 us; speedup vs baseline: 1.5695x; 1.5695x over previous
//
#include <hip/hip_runtime.h>
#include <math.h>

#define Bb 64
#define Pp 196
#define ENCd 2048
#define Lc 20
#define Tt 19
#define Vv 10000
#define Ee 512
#define Dd 512
#define Aa 512
#define K2 2560     // E + ENC  (x2 = [emb, gate*awe])
#define KG 3072     // E + ENC + D
#define G4 2048     // 4*D

#define OUT_PRED 0ll
#define OUT_CAPS 12160000ll   // B*T*V
#define OUT_ALPH 12161280ll   // + B*L
#define OUT_SIND 12399616ll   // + B*T*P

typedef unsigned short ushort_t;
typedef __attribute__((ext_vector_type(8))) short short8;
typedef __attribute__((ext_vector_type(4))) float f32x4;

#define MFMA16 __builtin_amdgcn_mfma_f32_16x16x32_bf16

__device__ __forceinline__ float b2f(ushort_t u) {
    union { unsigned int i; float f; } x; x.i = ((unsigned int)u) << 16; return x.f;
}
__device__ __forceinline__ ushort_t f2b(float f) {
    union { float f; unsigned int i; } x; x.f = f;
    unsigned int r = x.i + 0x7fffu + ((x.i >> 16) & 1u);
    return (ushort_t)(r >> 16);
}
__device__ __forceinline__ float fsig(float x) { return 1.0f / (1.0f + __expf(-x)); }
__device__ __forceinline__ float ftanh(float x) {
    x = fminf(fmaxf(x, -15.0f), 15.0f);
    float e = __expf(2.0f * x);
    return (e - 1.0f) / (e + 1.0f);
}

// ---------------- sort (stable descending argsort of caption lengths) --------
__global__ void k_sort(const int* __restrict__ cap_len, const int* __restrict__ caps_in,
                       float* __restrict__ out, int* __restrict__ sind,
                       int* __restrict__ dlen, int* __restrict__ caps_s) {
    __shared__ int cls[Bb];
    int i = threadIdx.x;
    int cl = cap_len[i];
    cls[i] = cl;
    __syncthreads();
    int rank = 0;
    for (int j = 0; j < Bb; ++j) {
        int cj = cls[j];
        rank += (cj > cl) || (cj == cl && j < i);
    }
    sind[rank] = i;
    dlen[rank] = cl - 1;
    out[OUT_SIND + rank] = (float)i;
    for (int l = 0; l < Lc; ++l) {
        int v = caps_in[i * Lc + l];
        caps_s[rank * Lc + l] = v;
        out[OUT_CAPS + rank * Lc + l] = (float)v;
    }
}

// ---------------- merged weight conversions ----------------------------------
__device__ __forceinline__ void cvtseg(const float* __restrict__ src, ushort_t* __restrict__ dst,
                                       int cols, int stride, int off, int bid0, long long quads) {
    long long qid = (long long)bid0 * 256 + threadIdx.x;
    if (qid >= quads) return;
    int c4pr = cols >> 2;
    int r = (int)(qid / c4pr), c4 = (int)(qid % c4pr) << 2;
    float4 v = *(const float4*)&src[(size_t)r * cols + c4];
    ushort4 o; o.x = f2b(v.x); o.y = f2b(v.y); o.z = f2b(v.z); o.w = f2b(v.w);
    *(ushort4*)&dst[(size_t)r * stride + off + c4] = o;
}

__global__ void k_cvtall(const float* Wdec, const float* Wfb, const float* Wih,
                         const float* Whh, const float* Wfc, const float* Wenc_f,
                         const float* Wih0, const float* Wic0,
                         ushort_t* W_ag, ushort_t* W_cat, ushort_t* W_fcb,
                         ushort_t* W_enc, ushort_t* W_hcb) {
    int b = blockIdx.x;
    if      (b < 256)   cvtseg(Wdec,  W_ag,               512,  512,  0,    b,         65536);
    else if (b < 1280)  cvtseg(Wfb,   W_ag + 512 * 512,   512,  512,  0,    b - 256,   262144);
    else if (b < 6400)  cvtseg(Wih,   W_cat,              2560, 3072, 0,    b - 1280,  1310720);
    else if (b < 7424)  cvtseg(Whh,   W_cat,              512,  3072, 2560, b - 6400,  262144);
    else if (b < 12424) cvtseg(Wfc,   W_fcb,              512,  512,  0,    b - 7424,  1280000);
    else if (b < 13448) cvtseg(Wenc_f,W_enc,              2048, 2048, 0,    b - 12424, 262144);
    else if (b < 14472) cvtseg(Wih0,  W_hcb,              2048, 2048, 0,    b - 13448, 262144);
    else                cvtseg(Wic0,  W_hcb + 512 * 2048, 2048, 2048, 0,    b - 14472, 262144);
}

// ---------------- bias prep --------------------------------------------------
__global__ void k_bias(const float* b_dec, const float* b_fb, const float* b_ihp,
                       const float* b_hhp, const float* b_h, const float* b_c,
                       float* b_ag, float* bsum, float* b_hc) {
    int id = blockIdx.x * 256 + threadIdx.x;
    if (id < 512) b_ag[id] = b_dec[id];
    else if (id < 2560) b_ag[id] = b_fb[id - 512];
    if (id < 2048) bsum[id] = b_ihp[id] + b_hhp[id];
    if (id < 512) b_hc[id] = b_h[id];
    else if (id < 1024) b_hc[id] = b_c[id - 512];
}

// ---------------- gather+convert encoder_out (sorted) -> bf16 ----------------
__global__ void __launch_bounds__(256) k_enccvt(const float* __restrict__ enc,
                                                const int* __restrict__ sind,
                                                ushort_t* __restrict__ enc_bf) {
    int r = blockIdx.x;                 // 12544 rows
    int b = r / Pp;
    size_t srow = (size_t)sind[b] * Pp + (r - b * Pp);
    int e8 = threadIdx.x * 8;
    const float* s = enc + srow * ENCd + e8;
    float4 v0 = *(const float4*)s;
    float4 v1 = *(const float4*)(s + 4);
    short8 o;
    o[0] = (short)f2b(v0.x); o[1] = (short)f2b(v0.y); o[2] = (short)f2b(v0.z); o[3] = (short)f2b(v0.w);
    o[4] = (short)f2b(v1.x); o[5] = (short)f2b(v1.y); o[6] = (short)f2b(v1.z); o[7] = (short)f2b(v1.w);
    *(short8*)&enc_bf[(size_t)r * ENCd + e8] = o;
}

// ---------------- mean over pixels (from bf16) -------------------------------
__global__ void __launch_bounds__(1024) k_meanenc(const ushort_t* __restrict__ enc_bf,
                                                  ushort_t* __restrict__ mean_bf) {
    int b = blockIdx.x;
    int lane = threadIdx.x & 63, w = threadIdx.x >> 6;
    int cg = w & 3, pg = w >> 2;                      // 4 col-groups, 4 p-groups
    int lc = cg * 512 + lane * 8;
    __shared__ float red[4][2048];
    float acc[8] = {};
    for (int p = pg; p < Pp; p += 4) {
        short8 v = *(const short8*)&enc_bf[((size_t)b * Pp + p) * ENCd + lc];
        #pragma unroll
        for (int j = 0; j < 8; ++j) acc[j] += b2f((ushort_t)v[j]);
    }
    #pragma unroll
    for (int j = 0; j < 8; ++j) red[pg][lc + j] = acc[j];
    __syncthreads();
    int tid = threadIdx.x;
    float2 s = {0.f, 0.f};
    #pragma unroll
    for (int g = 0; g < 4; ++g) {
        float2 v = *(const float2*)&red[g][tid * 2];
        s.x += v.x; s.y += v.y;
    }
    ushort2 o; o.x = f2b(s.x * (1.0f / Pp)); o.y = f2b(s.y * (1.0f / Pp));
    *(ushort2*)&mean_bf[(size_t)b * ENCd + tid * 2] = o;
}

// ---------------- att1 = enc_bf @ W_enc^T + b -> bf16  (grid (4,196)) --------
__global__ void __launch_bounds__(256) k_att1(const ushort_t* __restrict__ enc_bf,
                                              const ushort_t* __restrict__ Wenc,
                                              const float* __restrict__ benc,
                                              ushort_t* __restrict__ att1) {
    int lane = threadIdx.x & 63, w = threadIdx.x >> 6;
    int r16 = lane & 15, kq = (lane >> 4) << 3;
    int m0 = blockIdx.y * 64 + w * 16;
    int n0 = blockIdx.x * 128;
    f32x4 acc[8];
    #pragma unroll
    for (int j = 0; j < 8; ++j) acc[j] = (f32x4){0.f, 0.f, 0.f, 0.f};
    const ushort_t* ap = enc_bf + (size_t)(m0 + r16) * ENCd + kq;
    for (int k0 = 0; k0 < ENCd; k0 += 32) {
        short8 a = *(const short8*)(ap + k0);
        #pragma unroll
        for (int tt = 0; tt < 8; ++tt) {
            short8 bw = *(const short8*)&Wenc[(size_t)(n0 + tt * 16 + r16) * ENCd + k0 + kq];
            acc[tt] = MFMA16(a, bw, acc[tt], 0, 0, 0);
        }
    }
    int rj0 = (lane >> 4) << 2;
    #pragma unroll
    for (int tt = 0; tt < 8; ++tt)
        #pragma unroll
        for (int j = 0; j < 4; ++j) {
            int row = m0 + rj0 + j;
            int col = n0 + tt * 16 + r16;
            att1[(size_t)row * Aa + col] = f2b(acc[tt][j] + benc[col]);
        }
}

// ---------------- unified small GEMM, split-K over 4 waves -------------------
// M=64. MODE: 0=AG (att2|sigmoid gate), 1=GATES+LSTM, 3=H0C0
template<int NT, int MODE>
__global__ void __launch_bounds__(256) k_sgemm(
        const ushort_t* __restrict__ A, int lda,
        const ushort_t* __restrict__ W, int ldw, int K, int nblock, int nstride,
        const float* __restrict__ bias,
        float* __restrict__ of, const ushort_t* __restrict__ hin,
        ushort_t* __restrict__ hout, float* __restrict__ cst,
        const int* __restrict__ dlen, int t) {
    int lane = threadIdx.x & 63, w = threadIdx.x >> 6;
    int r16 = lane & 15, kq = (lane >> 4) << 3;
    int ncol[NT];
    #pragma unroll
    for (int tt = 0; tt < NT; ++tt) ncol[tt] = blockIdx.x * nblock + tt * nstride + r16;
    f32x4 acc[4][NT];
    #pragma unroll
    for (int mt = 0; mt < 4; ++mt)
        #pragma unroll
        for (int tt = 0; tt < NT; ++tt) acc[mt][tt] = (f32x4){0.f, 0.f, 0.f, 0.f};
    int kper = K >> 2;
    for (int k0 = w * kper; k0 < w * kper + kper; k0 += 32) {
        short8 a[4];
        #pragma unroll
        for (int mt = 0; mt < 4; ++mt) {
            const ushort_t* s;
            if (MODE == 1 && k0 >= K2) s = hin + (size_t)(mt * 16 + r16) * Dd + (k0 - K2) + kq;
            else                       s = A   + (size_t)(mt * 16 + r16) * lda + k0 + kq;
            a[mt] = *(const short8*)s;
        }
        #pragma unroll
        for (int tt = 0; tt < NT; ++tt) {
            short8 bw = *(const short8*)&W[(size_t)ncol[tt] * ldw + k0 + kq];
            #pragma unroll
            for (int mt = 0; mt < 4; ++mt)
                acc[mt][tt] = MFMA16(a[mt], bw, acc[mt][tt], 0, 0, 0);
        }
    }
    // split-K reduce across waves
    __shared__ float red[2][64][NT * 16 + 4];
    if (w >= 2) {
        float* row = &red[w - 2][lane][0];
        #pragma unroll
        for (int mt = 0; mt < 4; ++mt)
            #pragma unroll
            for (int tt = 0; tt < NT; ++tt) *(f32x4*)&row[(mt * NT + tt) * 4] = acc[mt][tt];
    }
    __syncthreads();
    if (w < 2) {
        float* row = &red[w][lane][0];
        #pragma unroll
        for (int mt = 0; mt < 4; ++mt)
            #pragma unroll
            for (int tt = 0; tt < NT; ++tt) acc[mt][tt] += *(f32x4*)&row[(mt * NT + tt) * 4];
    }
    __syncthreads();
    if (w == 1) {
        float* row = &red[0][lane][0];
        #pragma unroll
        for (int mt = 0; mt < 4; ++mt)
            #pragma unroll
            for (int tt = 0; tt < NT; ++tt) *(f32x4*)&row[(mt * NT + tt) * 4] = acc[mt][tt];
    }
    __syncthreads();
    if (w != 0) return;
    {
        float* row = &red[0][lane][0];
        #pragma unroll
        for (int mt = 0; mt < 4; ++mt)
            #pragma unroll
            for (int tt = 0; tt < NT; ++tt) acc[mt][tt] += *(f32x4*)&row[(mt * NT + tt) * 4];
    }
    int rj0 = (lane >> 4) << 2;
    if (MODE == 0) {
        int col = ncol[0];
        float bv = bias[col];
        #pragma unroll
        for (int mt = 0; mt < 4; ++mt)
            #pragma unroll
            for (int j = 0; j < 4; ++j) {
                int row = mt * 16 + rj0 + j;
                float v = acc[mt][0][j] + bv;
                of[(size_t)row * K2 + col] = (col >= 512) ? fsig(v) : v;
            }
    } else if (MODE == 1) {
        int d = ncol[0];
        float bi = bias[d], bf_ = bias[d + 512], bg = bias[d + 1024], bo = bias[d + 1536];
        #pragma unroll
        for (int mt = 0; mt < 4; ++mt)
            #pragma unroll
            for (int j = 0; j < 4; ++j) {
                int row = mt * 16 + rj0 + j;
                ushort_t hb;
                if (t < dlen[row]) {
                    float gi = acc[mt][0][j] + bi, gf = acc[mt][1][j] + bf_;
                    float gg = acc[mt][2][j] + bg, go = acc[mt][3][j] + bo;
                    float cv = cst[row * Dd + d];
                    float cn = fsig(gf) * cv + fsig(gi) * ftanh(gg);
                    float hn = fsig(go) * ftanh(cn);
                    cst[row * Dd + d] = cn;
                    hb = f2b(hn);
                } else {
                    hb = hin[row * Dd + d];
                }
                hout[row * Dd + d] = hb;
            }
    } else {  // MODE 3: h0 / c0
        #pragma unroll
        for (int mt = 0; mt < 4; ++mt)
            #pragma unroll
            for (int tt = 0; tt < NT; ++tt) {
                int col = ncol[tt];
                float bv = bias[col];
                #pragma unroll
                for (int j = 0; j < 4; ++j) {
                    int row = mt * 16 + rj0 + j;
                    float v = acc[mt][tt][j] + bv;
                    if (col < 512) hout[row * Dd + col] = f2b(v);
                    else           cst[row * Dd + (col - 512)] = v;
                }
            }
    }
}

// ---------------- fused e-score + softmax + awe + x2 write + emb gather ------
__global__ void __launch_bounds__(1024) k_esmawe(
        const ushort_t* __restrict__ att1, const float* __restrict__ ag,
        const float* __restrict__ wfull, const float* __restrict__ bfull,
        const ushort_t* __restrict__ enc_bf,
        const float* __restrict__ emb, const int* __restrict__ caps_s,
        ushort_t* __restrict__ x2, float* __restrict__ out,
        const int* __restrict__ dlen, int t) {
    int b = blockIdx.x;
    int tid = threadIdx.x;
    int lane = tid & 63, w = tid >> 6;
    __shared__ float att2f[512], wfl[512];
    __shared__ float e_sh[200], al_sh[200], sm[256];
    if (tid < 512) att2f[tid] = ag[(size_t)b * K2 + tid];
    else           wfl[tid - 512] = wfull[tid - 512];
    __syncthreads();
    // e-scores
    for (int p = w; p < Pp; p += 16) {
        short8 a1 = *(const short8*)&att1[((size_t)b * Pp + p) * Aa + lane * 8];
        float s = 0.f;
        #pragma unroll
        for (int j = 0; j < 8; ++j)
            s += ftanh(b2f((ushort_t)a1[j]) + att2f[lane * 8 + j]) * wfl[lane * 8 + j];
        #pragma unroll
        for (int o = 32; o; o >>= 1) s += __shfl_xor(s, o);
        if (lane == 0) e_sh[p] = s + bfull[0];
    }
    __syncthreads();
    // softmax over 196
    float v = (tid < Pp) ? e_sh[tid] : -1e30f;
    if (tid < 256) sm[tid] = v;
    __syncthreads();
    for (int o = 128; o; o >>= 1) {
        if (tid < o) sm[tid] = fmaxf(sm[tid], sm[tid + o]);
        __syncthreads();
    }
    float mx = sm[0];
    __syncthreads();
    float ex = (tid < Pp) ? __expf(v - mx) : 0.0f;
    if (tid < 256) sm[tid] = ex;
    __syncthreads();
    for (int o = 128; o; o >>= 1) {
        if (tid < o) sm[tid] += sm[tid + o];
        __syncthreads();
    }
    float denom = sm[0];
    if (tid < Pp) {
        float al = ex / denom;
        al_sh[tid] = al;
        out[OUT_ALPH + ((long long)b * Tt + t) * Pp + tid] = (t < dlen[b]) ? al : 0.0f;
    }
    if (tid < 256) {   // emb gather -> x2[:, :512]
        float2 e2v = *(const float2*)&emb[(size_t)caps_s[b * Lc + t] * Ee + tid * 2];
        ushort2 o2; o2.x = f2b(e2v.x); o2.y = f2b(e2v.y);
        *(ushort2*)&x2[(size_t)b * K2 + tid * 2] = o2;
    }
    __syncthreads();
    // awe = alpha . enc ; x2[:, 512:] = bf16(gate * awe)
    int e2 = tid * 2;
    float s0 = 0.f, s1 = 0.f;
    const ushort_t* ep = enc_bf + (size_t)b * Pp * ENCd + e2;
    #pragma unroll 4
    for (int p = 0; p < Pp; ++p) {
        float a = al_sh[p];
        ushort2 vv = *(const ushort2*)(ep + (size_t)p * ENCd);
        s0 += a * b2f(vv.x); s1 += a * b2f(vv.y);
    }
    float2 g2 = *(const float2*)&ag[(size_t)b * K2 + 512 + e2];
    ushort2 o2; o2.x = f2b(g2.x * s0); o2.y = f2b(g2.y * s1);
    *(ushort2*)&x2[(size_t)b * K2 + Ee + e2] = o2;
}

// ---------------- batched preds: [19*64] x 10000 x 512 -----------------------
__global__ void __launch_bounds__(256) k_preds(
        const ushort_t* __restrict__ hball, const ushort_t* __restrict__ Wfc,
        const float* __restrict__ bfc, const int* __restrict__ dlen,
        float* __restrict__ out) {
    int lane = threadIdx.x & 63, w = threadIdx.x >> 6;
    int r16 = lane & 15, kq = (lane >> 4) << 3, rj0 = (lane >> 4) << 2;
    int ts = blockIdx.y;                 // 0..18
    int n0 = blockIdx.x * 80;
    const ushort_t* ap = hball + (size_t)((ts + 1) * Bb + w * 16 + r16) * Dd + kq;
    f32x4 acc[5];
    #pragma unroll
    for (int j = 0; j < 5; ++j) acc[j] = (f32x4){0.f, 0.f, 0.f, 0.f};
    for (int k0 = 0; k0 < Dd; k0 += 32) {
        short8 a = *(const short8*)(ap + k0);
        #pragma unroll
        for (int tt = 0; tt < 5; ++tt) {
            short8 bw = *(const short8*)&Wfc[(size_t)(n0 + tt * 16 + r16) * Dd + k0 + kq];
            acc[tt] = MFMA16(a, bw, acc[tt], 0, 0, 0);
        }
    }
    #pragma unroll
    for (int tt = 0; tt < 5; ++tt) {
        int col = n0 + tt * 16 + r16;
        float bv = bfc[col];
        #pragma unroll
        for (int j = 0; j < 4; ++j) {
            int b = w * 16 + rj0 + j;
            out[OUT_PRED + ((long long)b * Tt + ts) * Vv + col] =
                (ts < dlen[b]) ? acc[tt][j] + bv : 0.0f;
        }
    }
}

extern "C" void kernel_launch(void* const* d_in, const int* in_sizes, int n_in,
                              void* d_out, int out_size, void* d_ws, size_t ws_size,
                              hipStream_t stream) {
    const float* encoder_out      = (const float*)d_in[0];
    const int*   encoded_captions = (const int*)d_in[1];
    const int*   caption_lengths  = (const int*)d_in[2];
    const float* emb       = (const float*)d_in[3];
    const float* W_ih      = (const float*)d_in[4];
    const float* b_ih      = (const float*)d_in[5];
    const float* W_hh      = (const float*)d_in[6];
    const float* b_hh      = (const float*)d_in[7];
    const float* W_init_h  = (const float*)d_in[8];
    const float* b_init_h  = (const float*)d_in[9];
    const float* W_init_c  = (const float*)d_in[10];
    const float* b_init_c  = (const float*)d_in[11];
    const float* W_fbeta   = (const float*)d_in[12];
    const float* b_fbeta   = (const float*)d_in[13];
    const float* W_fc      = (const float*)d_in[14];
    const float* b_fc      = (const float*)d_in[15];
    const float* W_enc_att = (const float*)d_in[16];
    const float* b_enc_att = (const float*)d_in[17];
    const float* W_dec_att = (const float*)d_in[18];
    const float* b_dec_att = (const float*)d_in[19];
    const float* W_full_att = (const float*)d_in[20];
    const float* b_full_att = (const float*)d_in[21];
    float* out = (float*)d_out;

    char* p = (char*)d_ws;
    auto alloc = [&](size_t bytes) { char* r = p; p += (bytes + 255) & ~255ull; return r; };
    int* sind   = (int*)alloc(64 * 4);
    int* dlen   = (int*)alloc(64 * 4);
    int* caps_s = (int*)alloc(Bb * Lc * 4);
    float* c_st  = (float*)alloc(Bb * Dd * 4);
    float* ag    = (float*)alloc((size_t)Bb * K2 * 4);
    float* b_ag  = (float*)alloc(K2 * 4);
    float* bsum  = (float*)alloc(G4 * 4);
    float* b_hc  = (float*)alloc(1024 * 4);
    ushort_t* mean_bf = (ushort_t*)alloc((size_t)Bb * ENCd * 2);
    ushort_t* hball   = (ushort_t*)alloc((size_t)(Tt + 1) * Bb * Dd * 2);  // 1.31 MB
    ushort_t* x2      = (ushort_t*)alloc((size_t)Bb * K2 * 2);
    ushort_t* att1    = (ushort_t*)alloc((size_t)Bb * Pp * Aa * 2);        // 12.85 MB
    ushort_t* W_enc   = (ushort_t*)alloc((size_t)Aa * ENCd * 2);           // 2 MB
    ushort_t* W_ag    = (ushort_t*)alloc((size_t)K2 * Dd * 2);             // 2.6 MB
    ushort_t* W_cat   = (ushort_t*)alloc((size_t)G4 * KG * 2);             // 12.6 MB
    ushort_t* W_fcb   = (ushort_t*)alloc((size_t)Vv * Dd * 2);             // 10.2 MB
    ushort_t* W_hcb   = (ushort_t*)alloc((size_t)1024 * ENCd * 2);         // 4.2 MB
    ushort_t* enc_bf  = (ushort_t*)alloc((size_t)Bb * Pp * ENCd * 2);      // 51.4 MB

    k_sort<<<1, 64, 0, stream>>>(caption_lengths, encoded_captions, out, sind, dlen, caps_s);
    k_cvtall<<<15496, 256, 0, stream>>>(W_dec_att, W_fbeta, W_ih, W_hh, W_fc, W_enc_att,
                                        W_init_h, W_init_c, W_ag, W_cat, W_fcb, W_enc, W_hcb);
    k_bias<<<10, 256, 0, stream>>>(b_dec_att, b_fbeta, b_ih, b_hh, b_init_h, b_init_c,
                                   b_ag, bsum, b_hc);
    k_enccvt<<<12544, 256, 0, stream>>>(encoder_out, sind, enc_bf);
    k_meanenc<<<64, 1024, 0, stream>>>(enc_bf, mean_bf);
    // h0/c0 -> hball[0], c_st
    k_sgemm<4, 3><<<16, 256, 0, stream>>>(mean_bf, ENCd, W_hcb, ENCd, ENCd, 64, 16,
        b_hc, nullptr, nullptr, hball, c_st, nullptr, 0);
    // att1
    k_att1<<<dim3(4, 196), 256, 0, stream>>>(enc_bf, W_enc, b_enc_att, att1);

    for (int t = 0; t < Tt; ++t) {
        const ushort_t* hcur = hball + (size_t)t * Bb * Dd;
        ushort_t* hnext = hball + (size_t)(t + 1) * Bb * Dd;
        // ag = h @ [W_dec;W_fbeta]^T  (att2 raw | sigmoid gate)
        k_sgemm<1, 0><<<160, 256, 0, stream>>>(hcur, Dd, W_ag, Dd, Dd, 16, 16,
            b_ag, ag, nullptr, nullptr, nullptr, nullptr, 0);
        // e-score + softmax + awe + x2 + emb gather
        k_esmawe<<<64, 1024, 0, stream>>>(att1, ag, W_full_att, b_full_att, enc_bf,
            emb, caps_s, x2, out, dlen, t);
        // gates + LSTM fused -> hball[t+1]
        k_sgemm<4, 1><<<32, 256, 0, stream>>>(x2, K2, W_cat, KG, KG, 16, 512,
            bsum, nullptr, hcur, hnext, c_st, dlen, t);
    }
    // batched preds over all (b, t)
    k_preds<<<dim3(125, 19), 256, 0, stream>>>(hball, W_fcb, b_fc, dlen, out);
}

// Round 7
// 1584.695 us; speedup vs baseline: 1.9185x; 1.2224x over previous
//
#include <hip/hip_runtime.h>
#include <math.h>

#define Bb 64
#define Pp 196
#define ENCd 2048
#define Lc 20
#define Tt 19
#define Vv 10000
#define Ee 512
#define Dd 512
#define Aa 512
#define K2 2560     // E + ENC  (x2 = [emb, gate*awe])
#define KG 3072     // E + ENC + D
#define G4 2048     // 4*D

#define OUT_PRED 0ll
#define OUT_CAPS 12160000ll   // B*T*V
#define OUT_ALPH 12161280ll   // + B*L
#define OUT_SIND 12399616ll   // + B*T*P

typedef unsigned short ushort_t;
typedef __attribute__((ext_vector_type(8))) short short8;
typedef __attribute__((ext_vector_type(4))) float f32x4;

#define MFMA16 __builtin_amdgcn_mfma_f32_16x16x32_bf16

__device__ __forceinline__ float b2f(ushort_t u) {
    union { unsigned int i; float f; } x; x.i = ((unsigned int)u) << 16; return x.f;
}
__device__ __forceinline__ ushort_t f2b(float f) {
    union { float f; unsigned int i; } x; x.f = f;
    unsigned int r = x.i + 0x7fffu + ((x.i >> 16) & 1u);
    return (ushort_t)(r >> 16);
}
__device__ __forceinline__ float fsig(float x) { return 1.0f / (1.0f + __expf(-x)); }
__device__ __forceinline__ float ftanh(float x) {
    x = fminf(fmaxf(x, -15.0f), 15.0f);
    float e = __expf(2.0f * x);
    return (e - 1.0f) / (e + 1.0f);
}

// ---------------- sort (stable descending argsort of caption lengths) --------
__global__ void k_sort(const int* __restrict__ cap_len, const int* __restrict__ caps_in,
                       float* __restrict__ out, int* __restrict__ sind,
                       int* __restrict__ dlen, int* __restrict__ caps_s) {
    __shared__ int cls[Bb];
    int i = threadIdx.x;
    int cl = cap_len[i];
    cls[i] = cl;
    __syncthreads();
    int rank = 0;
    for (int j = 0; j < Bb; ++j) {
        int cj = cls[j];
        rank += (cj > cl) || (cj == cl && j < i);
    }
    sind[rank] = i;
    dlen[rank] = cl - 1;
    out[OUT_SIND + rank] = (float)i;
    for (int l = 0; l < Lc; ++l) {
        int v = caps_in[i * Lc + l];
        caps_s[rank * Lc + l] = v;
        out[OUT_CAPS + rank * Lc + l] = (float)v;
    }
}

// ---------------- merged weight conversions ----------------------------------
__device__ __forceinline__ void cvtseg(const float* __restrict__ src, ushort_t* __restrict__ dst,
                                       int cols, int stride, int off, int bid0, long long quads) {
    long long qid = (long long)bid0 * 256 + threadIdx.x;
    if (qid >= quads) return;
    int c4pr = cols >> 2;
    int r = (int)(qid / c4pr), c4 = (int)(qid % c4pr) << 2;
    float4 v = *(const float4*)&src[(size_t)r * cols + c4];
    ushort4 o; o.x = f2b(v.x); o.y = f2b(v.y); o.z = f2b(v.z); o.w = f2b(v.w);
    *(ushort4*)&dst[(size_t)r * stride + off + c4] = o;
}

__global__ void k_cvtall(const float* Wdec, const float* Wfb, const float* Wih,
                         const float* Whh, const float* Wfc, const float* Wenc_f,
                         const float* Wih0, const float* Wic0,
                         ushort_t* W_ag, ushort_t* W_cat, ushort_t* W_fcb,
                         ushort_t* W_enc, ushort_t* W_hcb) {
    int b = blockIdx.x;
    if      (b < 256)   cvtseg(Wdec,  W_ag,               512,  512,  0,    b,         65536);
    else if (b < 1280)  cvtseg(Wfb,   W_ag + 512 * 512,   512,  512,  0,    b - 256,   262144);
    else if (b < 6400)  cvtseg(Wih,   W_cat,              2560, 3072, 0,    b - 1280,  1310720);
    else if (b < 7424)  cvtseg(Whh,   W_cat,              512,  3072, 2560, b - 6400,  262144);
    else if (b < 12424) cvtseg(Wfc,   W_fcb,              512,  512,  0,    b - 7424,  1280000);
    else if (b < 13448) cvtseg(Wenc_f,W_enc,              2048, 2048, 0,    b - 12424, 262144);
    else if (b < 14472) cvtseg(Wih0,  W_hcb,              2048, 2048, 0,    b - 13448, 262144);
    else                cvtseg(Wic0,  W_hcb + 512 * 2048, 2048, 2048, 0,    b - 14472, 262144);
}

// ---------------- bias prep --------------------------------------------------
__global__ void k_bias(const float* b_dec, const float* b_fb, const float* b_ihp,
                       const float* b_hhp, const float* b_h, const float* b_c,
                       float* b_ag, float* bsum, float* b_hc) {
    int id = blockIdx.x * 256 + threadIdx.x;
    if (id < 512) b_ag[id] = b_dec[id];
    else if (id < 2560) b_ag[id] = b_fb[id - 512];
    if (id < 2048) bsum[id] = b_ihp[id] + b_hhp[id];
    if (id < 512) b_hc[id] = b_h[id];
    else if (id < 1024) b_hc[id] = b_c[id - 512];
}

// ---------------- gather+convert encoder_out (sorted) -> bf16 ----------------
__global__ void __launch_bounds__(256) k_enccvt(const float* __restrict__ enc,
                                                const int* __restrict__ sind,
                                                ushort_t* __restrict__ enc_bf) {
    int r = blockIdx.x;                 // 12544 rows
    int b = r / Pp;
    size_t srow = (size_t)sind[b] * Pp + (r - b * Pp);
    int e8 = threadIdx.x * 8;
    const float* s = enc + srow * ENCd + e8;
    float4 v0 = *(const float4*)s;
    float4 v1 = *(const float4*)(s + 4);
    short8 o;
    o[0] = (short)f2b(v0.x); o[1] = (short)f2b(v0.y); o[2] = (short)f2b(v0.z); o[3] = (short)f2b(v0.w);
    o[4] = (short)f2b(v1.x); o[5] = (short)f2b(v1.y); o[6] = (short)f2b(v1.z); o[7] = (short)f2b(v1.w);
    *(short8*)&enc_bf[(size_t)r * ENCd + e8] = o;
}

// ---------------- mean over pixels (from bf16) -------------------------------
__global__ void __launch_bounds__(1024) k_meanenc(const ushort_t* __restrict__ enc_bf,
                                                  ushort_t* __restrict__ mean_bf) {
    int b = blockIdx.x;
    int lane = threadIdx.x & 63, w = threadIdx.x >> 6;
    int cg = w & 3, pg = w >> 2;
    int lc = cg * 512 + lane * 8;
    __shared__ float red[4][2048];
    float acc[8] = {};
    for (int p = pg; p < Pp; p += 4) {
        short8 v = *(const short8*)&enc_bf[((size_t)b * Pp + p) * ENCd + lc];
        #pragma unroll
        for (int j = 0; j < 8; ++j) acc[j] += b2f((ushort_t)v[j]);
    }
    #pragma unroll
    for (int j = 0; j < 8; ++j) red[pg][lc + j] = acc[j];
    __syncthreads();
    int tid = threadIdx.x;
    float2 s = {0.f, 0.f};
    #pragma unroll
    for (int g = 0; g < 4; ++g) {
        float2 v = *(const float2*)&red[g][tid * 2];
        s.x += v.x; s.y += v.y;
    }
    ushort2 o; o.x = f2b(s.x * (1.0f / Pp)); o.y = f2b(s.y * (1.0f / Pp));
    *(ushort2*)&mean_bf[(size_t)b * ENCd + tid * 2] = o;
}

// ---------------- att1 = enc_bf @ W_enc^T + b -> bf16  (grid (8,98)) ---------
// block = 128 rows x 64 cols; wave = 32 rows x 64 cols (2 A + 4 B -> 8 MFMA)
__global__ void __launch_bounds__(256) k_att1(const ushort_t* __restrict__ enc_bf,
                                              const ushort_t* __restrict__ Wenc,
                                              const float* __restrict__ benc,
                                              ushort_t* __restrict__ att1) {
    int lane = threadIdx.x & 63, w = threadIdx.x >> 6;
    int r16 = lane & 15, kq = (lane >> 4) << 3;
    int m0 = blockIdx.y * 128 + w * 32;
    int n0 = blockIdx.x * 64;
    f32x4 acc[2][4];
    #pragma unroll
    for (int i = 0; i < 2; ++i)
        #pragma unroll
        for (int j = 0; j < 4; ++j) acc[i][j] = (f32x4){0.f, 0.f, 0.f, 0.f};
    const ushort_t* ap0 = enc_bf + (size_t)(m0 + r16) * ENCd + kq;
    const ushort_t* ap1 = ap0 + (size_t)16 * ENCd;
    for (int k0 = 0; k0 < ENCd; k0 += 32) {
        short8 a0 = *(const short8*)(ap0 + k0);
        short8 a1 = *(const short8*)(ap1 + k0);
        #pragma unroll
        for (int tt = 0; tt < 4; ++tt) {
            short8 bw = *(const short8*)&Wenc[(size_t)(n0 + tt * 16 + r16) * ENCd + k0 + kq];
            acc[0][tt] = MFMA16(a0, bw, acc[0][tt], 0, 0, 0);
            acc[1][tt] = MFMA16(a1, bw, acc[1][tt], 0, 0, 0);
        }
    }
    int rj0 = (lane >> 4) << 2;
    #pragma unroll
    for (int mf = 0; mf < 2; ++mf)
        #pragma unroll
        for (int tt = 0; tt < 4; ++tt)
            #pragma unroll
            for (int j = 0; j < 4; ++j) {
                int row = m0 + mf * 16 + rj0 + j;
                int col = n0 + tt * 16 + r16;
                att1[(size_t)row * Aa + col] = f2b(acc[mf][tt][j] + benc[col]);
            }
}

// ---------------- unified small GEMM, split-K over 4 waves -------------------
// M=64. MODE: 0=AG (att2|sigmoid gate), 3=H0C0
template<int NT, int MODE>
__global__ void __launch_bounds__(256) k_sgemm(
        const ushort_t* __restrict__ A, int lda,
        const ushort_t* __restrict__ W, int ldw, int K, int nblock, int nstride,
        const float* __restrict__ bias,
        float* __restrict__ of, ushort_t* __restrict__ hout, float* __restrict__ cst) {
    int lane = threadIdx.x & 63, w = threadIdx.x >> 6;
    int r16 = lane & 15, kq = (lane >> 4) << 3;
    int ncol[NT];
    #pragma unroll
    for (int tt = 0; tt < NT; ++tt) ncol[tt] = blockIdx.x * nblock + tt * nstride + r16;
    f32x4 acc[4][NT];
    #pragma unroll
    for (int mt = 0; mt < 4; ++mt)
        #pragma unroll
        for (int tt = 0; tt < NT; ++tt) acc[mt][tt] = (f32x4){0.f, 0.f, 0.f, 0.f};
    int kper = K >> 2;
    for (int k0 = w * kper; k0 < w * kper + kper; k0 += 32) {
        short8 a[4];
        #pragma unroll
        for (int mt = 0; mt < 4; ++mt)
            a[mt] = *(const short8*)(A + (size_t)(mt * 16 + r16) * lda + k0 + kq);
        #pragma unroll
        for (int tt = 0; tt < NT; ++tt) {
            short8 bw = *(const short8*)&W[(size_t)ncol[tt] * ldw + k0 + kq];
            #pragma unroll
            for (int mt = 0; mt < 4; ++mt)
                acc[mt][tt] = MFMA16(a[mt], bw, acc[mt][tt], 0, 0, 0);
        }
    }
    __shared__ float red[2][64][NT * 16 + 4];
    if (w >= 2) {
        float* row = &red[w - 2][lane][0];
        #pragma unroll
        for (int mt = 0; mt < 4; ++mt)
            #pragma unroll
            for (int tt = 0; tt < NT; ++tt) *(f32x4*)&row[(mt * NT + tt) * 4] = acc[mt][tt];
    }
    __syncthreads();
    if (w < 2) {
        float* row = &red[w][lane][0];
        #pragma unroll
        for (int mt = 0; mt < 4; ++mt)
            #pragma unroll
            for (int tt = 0; tt < NT; ++tt) acc[mt][tt] += *(f32x4*)&row[(mt * NT + tt) * 4];
    }
    __syncthreads();
    if (w == 1) {
        float* row = &red[0][lane][0];
        #pragma unroll
        for (int mt = 0; mt < 4; ++mt)
            #pragma unroll
            for (int tt = 0; tt < NT; ++tt) *(f32x4*)&row[(mt * NT + tt) * 4] = acc[mt][tt];
    }
    __syncthreads();
    if (w != 0) return;
    {
        float* row = &red[0][lane][0];
        #pragma unroll
        for (int mt = 0; mt < 4; ++mt)
            #pragma unroll
            for (int tt = 0; tt < NT; ++tt) acc[mt][tt] += *(f32x4*)&row[(mt * NT + tt) * 4];
    }
    int rj0 = (lane >> 4) << 2;
    if (MODE == 0) {
        int col = ncol[0];
        float bv = bias[col];
        #pragma unroll
        for (int mt = 0; mt < 4; ++mt)
            #pragma unroll
            for (int j = 0; j < 4; ++j) {
                int row = mt * 16 + rj0 + j;
                float v = acc[mt][0][j] + bv;
                of[(size_t)row * K2 + col] = (col >= 512) ? fsig(v) : v;
            }
    } else {  // MODE 3: h0 / c0
        #pragma unroll
        for (int mt = 0; mt < 4; ++mt)
            #pragma unroll
            for (int tt = 0; tt < NT; ++tt) {
                int col = ncol[tt];
                float bv = bias[col];
                #pragma unroll
                for (int j = 0; j < 4; ++j) {
                    int row = mt * 16 + rj0 + j;
                    float v = acc[mt][tt][j] + bv;
                    if (col < 512) hout[row * Dd + col] = f2b(v);
                    else           cst[row * Dd + (col - 512)] = v;
                }
            }
    }
}

// ---------------- gates GEMM + LSTM, grid (32 d-tiles, 4 m-tiles) ------------
__global__ void __launch_bounds__(256) k_gates(
        const ushort_t* __restrict__ x2, const ushort_t* __restrict__ hin,
        const ushort_t* __restrict__ Wcat, const float* __restrict__ bsum,
        ushort_t* __restrict__ hout, float* __restrict__ cst,
        const int* __restrict__ dlen, int t) {
    int lane = threadIdx.x & 63, w = threadIdx.x >> 6;
    int r16 = lane & 15, kq = (lane >> 4) << 3;
    int m0 = blockIdx.y * 16;
    int d0 = blockIdx.x * 16;
    int row = m0 + r16;
    f32x4 acc[4];
    #pragma unroll
    for (int tt = 0; tt < 4; ++tt) acc[tt] = (f32x4){0.f, 0.f, 0.f, 0.f};
    for (int k0 = w * 768; k0 < w * 768 + 768; k0 += 32) {
        const ushort_t* s = (k0 < K2) ? (x2 + (size_t)row * K2 + k0 + kq)
                                      : (hin + (size_t)row * Dd + (k0 - K2) + kq);
        short8 a = *(const short8*)s;
        #pragma unroll
        for (int tt = 0; tt < 4; ++tt) {
            short8 bw = *(const short8*)&Wcat[(size_t)(d0 + tt * 512 + r16) * KG + k0 + kq];
            acc[tt] = MFMA16(a, bw, acc[tt], 0, 0, 0);
        }
    }
    __shared__ float red[2][64][20];
    if (w >= 2) {
        float* rr = &red[w - 2][lane][0];
        #pragma unroll
        for (int tt = 0; tt < 4; ++tt) *(f32x4*)&rr[tt * 4] = acc[tt];
    }
    __syncthreads();
    if (w < 2) {
        float* rr = &red[w][lane][0];
        #pragma unroll
        for (int tt = 0; tt < 4; ++tt) acc[tt] += *(f32x4*)&rr[tt * 4];
    }
    __syncthreads();
    if (w == 1) {
        float* rr = &red[0][lane][0];
        #pragma unroll
        for (int tt = 0; tt < 4; ++tt) *(f32x4*)&rr[tt * 4] = acc[tt];
    }
    __syncthreads();
    if (w != 0) return;
    {
        float* rr = &red[0][lane][0];
        #pragma unroll
        for (int tt = 0; tt < 4; ++tt) acc[tt] += *(f32x4*)&rr[tt * 4];
    }
    int rj0 = (lane >> 4) << 2;
    int d = d0 + r16;
    #pragma unroll
    for (int j = 0; j < 4; ++j) {
        int rw = m0 + rj0 + j;
        ushort_t hb;
        if (t < dlen[rw]) {
            float gi = acc[0][j] + bsum[d];
            float gf = acc[1][j] + bsum[512 + d];
            float gg = acc[2][j] + bsum[1024 + d];
            float go = acc[3][j] + bsum[1536 + d];
            float cv = cst[rw * Dd + d];
            float cn = fsig(gf) * cv + fsig(gi) * ftanh(gg);
            cst[rw * Dd + d] = cn;
            hb = f2b(fsig(go) * ftanh(cn));
        } else {
            hb = hin[rw * Dd + d];
        }
        hout[rw * Dd + d] = hb;
    }
}

// ---------------- fused e-score + softmax + awe(short8) + x2 + emb gather ----
__global__ void __launch_bounds__(1024) k_esmawe(
        const ushort_t* __restrict__ att1, const float* __restrict__ ag,
        const float* __restrict__ wfull, const float* __restrict__ bfull,
        const ushort_t* __restrict__ enc_bf,
        const float* __restrict__ emb, const int* __restrict__ caps_s,
        ushort_t* __restrict__ x2, float* __restrict__ out,
        const int* __restrict__ dlen, int t) {
    int b = blockIdx.x;
    int tid = threadIdx.x;
    int lane = tid & 63, w = tid >> 6;
    __shared__ float att2f[512], wfl[512];
    __shared__ float e_sh[200], al_sh[200], sm[256];
    __shared__ float redA[4][2048];     // 32 KB awe reduce
    if (tid < 512) att2f[tid] = ag[(size_t)b * K2 + tid];
    else           wfl[tid - 512] = wfull[tid - 512];
    __syncthreads();
    // e-scores
    for (int p = w; p < Pp; p += 16) {
        short8 a1 = *(const short8*)&att1[((size_t)b * Pp + p) * Aa + lane * 8];
        float s = 0.f;
        #pragma unroll
        for (int j = 0; j < 8; ++j)
            s += ftanh(b2f((ushort_t)a1[j]) + att2f[lane * 8 + j]) * wfl[lane * 8 + j];
        #pragma unroll
        for (int o = 32; o; o >>= 1) s += __shfl_xor(s, o);
        if (lane == 0) e_sh[p] = s + bfull[0];
    }
    __syncthreads();
    // softmax over 196
    float v = (tid < Pp) ? e_sh[tid] : -1e30f;
    if (tid < 256) sm[tid] = v;
    __syncthreads();
    for (int o = 128; o; o >>= 1) {
        if (tid < o) sm[tid] = fmaxf(sm[tid], sm[tid + o]);
        __syncthreads();
    }
    float mx = sm[0];
    __syncthreads();
    float ex = (tid < Pp) ? __expf(v - mx) : 0.0f;
    if (tid < 256) sm[tid] = ex;
    __syncthreads();
    for (int o = 128; o; o >>= 1) {
        if (tid < o) sm[tid] += sm[tid + o];
        __syncthreads();
    }
    float denom = sm[0];
    if (tid < Pp) {
        float al = ex / denom;
        al_sh[tid] = al;
        out[OUT_ALPH + ((long long)b * Tt + t) * Pp + tid] = (t < dlen[b]) ? al : 0.0f;
    }
    if (tid < 256) {   // emb gather -> x2[:, :512]
        float2 e2v = *(const float2*)&emb[(size_t)caps_s[b * Lc + t] * Ee + tid * 2];
        ushort2 o2; o2.x = f2b(e2v.x); o2.y = f2b(e2v.y);
        *(ushort2*)&x2[(size_t)b * K2 + tid * 2] = o2;
    }
    __syncthreads();
    // awe = alpha . enc  (short8 loads: thread (pg=tid>>8, cg=tid&255) does 8 cols)
    {
        int cg = tid & 255, pg = tid >> 8;     // 256 col-groups x 4 p-groups
        int c0 = cg * 8;
        float acc[8] = {};
        const ushort_t* ep = enc_bf + (size_t)b * Pp * ENCd + c0;
        for (int p = pg; p < Pp; p += 4) {
            float a = al_sh[p];
            short8 vv = *(const short8*)(ep + (size_t)p * ENCd);
            #pragma unroll
            for (int j = 0; j < 8; ++j) acc[j] += a * b2f((ushort_t)vv[j]);
        }
        *(f32x4*)&redA[pg][c0]     = *(f32x4*)&acc[0];
        *(f32x4*)&redA[pg][c0 + 4] = *(f32x4*)&acc[4];
    }
    __syncthreads();
    {
        int c2 = tid * 2;
        float s0 = redA[0][c2] + redA[1][c2] + redA[2][c2] + redA[3][c2];
        float s1 = redA[0][c2 + 1] + redA[1][c2 + 1] + redA[2][c2 + 1] + redA[3][c2 + 1];
        float2 g2 = *(const float2*)&ag[(size_t)b * K2 + 512 + c2];
        ushort2 o2; o2.x = f2b(g2.x * s0); o2.y = f2b(g2.y * s1);
        *(ushort2*)&x2[(size_t)b * K2 + Ee + c2] = o2;
    }
}

// ---------------- batched preds: [19*64] x 10000 x 512 -----------------------
__global__ void __launch_bounds__(256) k_preds(
        const ushort_t* __restrict__ hball, const ushort_t* __restrict__ Wfc,
        const float* __restrict__ bfc, const int* __restrict__ dlen,
        float* __restrict__ out) {
    int lane = threadIdx.x & 63, w = threadIdx.x >> 6;
    int r16 = lane & 15, kq = (lane >> 4) << 3, rj0 = (lane >> 4) << 2;
    int ts = blockIdx.y;                 // 0..18
    int n0 = blockIdx.x * 80;
    const ushort_t* ap = hball + (size_t)((ts + 1) * Bb + w * 16 + r16) * Dd + kq;
    f32x4 acc[5];
    #pragma unroll
    for (int j = 0; j < 5; ++j) acc[j] = (f32x4){0.f, 0.f, 0.f, 0.f};
    for (int k0 = 0; k0 < Dd; k0 += 32) {
        short8 a = *(const short8*)(ap + k0);
        #pragma unroll
        for (int tt = 0; tt < 5; ++tt) {
            short8 bw = *(const short8*)&Wfc[(size_t)(n0 + tt * 16 + r16) * Dd + k0 + kq];
            acc[tt] = MFMA16(a, bw, acc[tt], 0, 0, 0);
        }
    }
    #pragma unroll
    for (int tt = 0; tt < 5; ++tt) {
        int col = n0 + tt * 16 + r16;
        float bv = bfc[col];
        #pragma unroll
        for (int j = 0; j < 4; ++j) {
            int b = w * 16 + rj0 + j;
            out[OUT_PRED + ((long long)b * Tt + ts) * Vv + col] =
                (ts < dlen[b]) ? acc[tt][j] + bv : 0.0f;
        }
    }
}

extern "C" void kernel_launch(void* const* d_in, const int* in_sizes, int n_in,
                              void* d_out, int out_size, void* d_ws, size_t ws_size,
                              hipStream_t stream) {
    const float* encoder_out      = (const float*)d_in[0];
    const int*   encoded_captions = (const int*)d_in[1];
    const int*   caption_lengths  = (const int*)d_in[2];
    const float* emb       = (const float*)d_in[3];
    const float* W_ih      = (const float*)d_in[4];
    const float* b_ih      = (const float*)d_in[5];
    const float* W_hh      = (const float*)d_in[6];
    const float* b_hh      = (const float*)d_in[7];
    const float* W_init_h  = (const float*)d_in[8];
    const float* b_init_h  = (const float*)d_in[9];
    const float* W_init_c  = (const float*)d_in[10];
    const float* b_init_c  = (const float*)d_in[11];
    const float* W_fbeta   = (const float*)d_in[12];
    const float* b_fbeta   = (const float*)d_in[13];
    const float* W_fc      = (const float*)d_in[14];
    const float* b_fc      = (const float*)d_in[15];
    const float* W_enc_att = (const float*)d_in[16];
    const float* b_enc_att = (const float*)d_in[17];
    const float* W_dec_att = (const float*)d_in[18];
    const float* b_dec_att = (const float*)d_in[19];
    const float* W_full_att = (const float*)d_in[20];
    const float* b_full_att = (const float*)d_in[21];
    float* out = (float*)d_out;

    char* p = (char*)d_ws;
    auto alloc = [&](size_t bytes) { char* r = p; p += (bytes + 255) & ~255ull; return r; };
    int* sind   = (int*)alloc(64 * 4);
    int* dlen   = (int*)alloc(64 * 4);
    int* caps_s = (int*)alloc(Bb * Lc * 4);
    float* c_st  = (float*)alloc(Bb * Dd * 4);
    float* ag    = (float*)alloc((size_t)Bb * K2 * 4);
    float* b_ag  = (float*)alloc(K2 * 4);
    float* bsum  = (float*)alloc(G4 * 4);
    float* b_hc  = (float*)alloc(1024 * 4);
    ushort_t* mean_bf = (ushort_t*)alloc((size_t)Bb * ENCd * 2);
    ushort_t* hball   = (ushort_t*)alloc((size_t)(Tt + 1) * Bb * Dd * 2);  // 1.31 MB
    ushort_t* x2      = (ushort_t*)alloc((size_t)Bb * K2 * 2);
    ushort_t* att1    = (ushort_t*)alloc((size_t)Bb * Pp * Aa * 2);        // 12.85 MB
    ushort_t* W_enc   = (ushort_t*)alloc((size_t)Aa * ENCd * 2);           // 2 MB
    ushort_t* W_ag    = (ushort_t*)alloc((size_t)K2 * Dd * 2);             // 2.6 MB
    ushort_t* W_cat   = (ushort_t*)alloc((size_t)G4 * KG * 2);             // 12.6 MB
    ushort_t* W_fcb   = (ushort_t*)alloc((size_t)Vv * Dd * 2);             // 10.2 MB
    ushort_t* W_hcb   = (ushort_t*)alloc((size_t)1024 * ENCd * 2);         // 4.2 MB
    ushort_t* enc_bf  = (ushort_t*)alloc((size_t)Bb * Pp * ENCd * 2);      // 51.4 MB

    k_sort<<<1, 64, 0, stream>>>(caption_lengths, encoded_captions, out, sind, dlen, caps_s);
    k_cvtall<<<15496, 256, 0, stream>>>(W_dec_att, W_fbeta, W_ih, W_hh, W_fc, W_enc_att,
                                        W_init_h, W_init_c, W_ag, W_cat, W_fcb, W_enc, W_hcb);
    k_bias<<<10, 256, 0, stream>>>(b_dec_att, b_fbeta, b_ih, b_hh, b_init_h, b_init_c,
                                   b_ag, bsum, b_hc);
    k_enccvt<<<12544, 256, 0, stream>>>(encoder_out, sind, enc_bf);
    k_meanenc<<<64, 1024, 0, stream>>>(enc_bf, mean_bf);
    // h0/c0 -> hball[0], c_st
    k_sgemm<4, 3><<<16, 256, 0, stream>>>(mean_bf, ENCd, W_hcb, ENCd, ENCd, 64, 16,
        b_hc, nullptr, hball, c_st);
    // att1
    k_att1<<<dim3(8, 98), 256, 0, stream>>>(enc_bf, W_enc, b_enc_att, att1);

    for (int t = 0; t < Tt; ++t) {
        const ushort_t* hcur = hball + (size_t)t * Bb * Dd;
        ushort_t* hnext = hball + (size_t)(t + 1) * Bb * Dd;
        // ag = h @ [W_dec;W_fbeta]^T  (att2 raw | sigmoid gate)
        k_sgemm<1, 0><<<160, 256, 0, stream>>>(hcur, Dd, W_ag, Dd, Dd, 16, 16,
            b_ag, ag, nullptr, nullptr);
        // e-score + softmax + awe + x2 + emb gather
        k_esmawe<<<64, 1024, 0, stream>>>(att1, ag, W_full_att, b_full_att, enc_bf,
            emb, caps_s, x2, out, dlen, t);
        // gates + LSTM fused -> hball[t+1]
        k_gates<<<dim3(32, 4), 256, 0, stream>>>(x2, hcur, W_cat, bsum, hnext, c_st, dlen, t);
    }
    // batched preds over all (b, t)
    k_preds<<<dim3(125, 19), 256, 0, stream>>>(hball, W_fcb, b_fc, dlen, out);
}